// Round 4
// baseline (117.547 us; speedup 1.0000x reference)
//
#include <hip/hip_runtime.h>
#include <cstdint>
#include <cstddef>

typedef __bf16 bf16x8 __attribute__((ext_vector_type(8)));
typedef __bf16 bf16x4 __attribute__((ext_vector_type(4)));
typedef float f32x4 __attribute__((ext_vector_type(4)));
typedef unsigned short u16x4 __attribute__((ext_vector_type(4)));
typedef unsigned short u16x8 __attribute__((ext_vector_type(8)));

#define MFMA16(a, b, c) __builtin_amdgcn_mfma_f32_16x16x32_bf16(a, b, c, 0, 0, 0)

// async global->LDS, 16B per lane, LDS dest = wave-uniform base + lane*16
#define GLOAD16(g, l)                                                          \
    __builtin_amdgcn_global_load_lds(                                          \
        (const __attribute__((address_space(1))) unsigned int*)(g),            \
        (__attribute__((address_space(3))) unsigned int*)(l), 16, 0, 0)

__device__ __forceinline__ unsigned short f2bf(float f) {
    unsigned u = __builtin_bit_cast(unsigned, f);
    u = (u + 0x7FFFu + ((u >> 16) & 1u)) >> 16;   // RNE
    return (unsigned short)u;
}

// ---------------------------------------------------------------- prep:
// blocks [0,1024)    : pe[n][d]  (f32, n-major)
// blocks [1024,1280) : peT[d][n] (f32, d-major) for the V-transposed epilogue
// blocks [1280,2048) : weights f32 -> bf16, chunked per (d-tile, k-tile):
//   1KB chunk = [d&15][slot][e]; slot = (kq>>1) ^ ((d16>>1)&3)  (bank swizzle)
__global__ __launch_bounds__(256)
void prep(float* __restrict__ pe, float* __restrict__ peT, unsigned short* __restrict__ Wb,
          const float* __restrict__ w0, const float* __restrict__ w1,
          const float* __restrict__ w2, const float* __restrict__ w3) {
    const int bx = blockIdx.x, t = threadIdx.x;
    const float LC = 0.03597789207808881f;  // ln(10000)/256
    if (bx < 1024) {
        int n = bx, d = t;
        float div = expf(-(float)(2 * (d >> 1)) * LC);
        float ang = (float)n * div;
        pe[n * 256 + d] = (d & 1) ? cosf(ang) : sinf(ang);
    } else if (bx < 1280) {
        int d = bx - 1024;
        float div = expf(-(float)(2 * (d >> 1)) * LC);
        f32x4 o;
        int n0 = t * 4;
#pragma unroll
        for (int e = 0; e < 4; ++e) {
            float ang = (float)(n0 + e) * div;
            o[e] = (d & 1) ? cosf(ang) : sinf(ang);
        }
        *(f32x4*)&peT[(size_t)d * 1024 + n0] = o;
    } else {
        int i = bx - 1280;                 // 0..767, 192 blocks per tensor
        int tensor = i / 192, blk = i - tensor * 192;
        const float* w = (tensor == 0) ? w0 : (tensor == 1) ? w1 : (tensor == 2) ? w2 : w3;
        int idx4 = blk * 256 + t;          // f32x4 index
        int d = idx4 / 192;                // 192 quads per 768-row
        int kq4 = idx4 - d * 192;          // k-quad 0..191
        f32x4 v = *(const f32x4*)(w + (size_t)idx4 * 4);
        u16x4 o;
#pragma unroll
        for (int e = 0; e < 4; ++e) o[e] = f2bf(v[e]);
        int d16 = d & 15, kq_in = kq4 & 7;
        int slot = (kq_in >> 1) ^ ((d16 >> 1) & 3);
        unsigned short* dst = Wb + (size_t)tensor * 196608
                            + (d >> 4) * 12288 + (kq4 >> 3) * 512
                            + d16 * 32 + slot * 8 + (kq_in & 1) * 4;
        *(u16x4*)dst = o;
    }
}

// ---------------------------------------------------------------- patch embed v4
// 128 patches x 128 d per block, 4 waves (2 patch-halves x 2 d-halves), BK=32,
// 24 K-steps. ALL staging via global_load_lds; counted vmcnt(6) (never 0 in
// steady state) across raw s_barriers; A kept f32 in LDS, cvt at frag read.
struct EArgs {
    const float* src;
    const unsigned short* Wb;   // chunked/swizzled bf16 weights (196608 elems)
    const float* bias;
    const float* pe;            // (1024,256) n-major
    const float* peT;           // (256,1024) d-major
    unsigned short* dst;
    int Np, lgNp, lgG, S, trans;
};

template<bool TR>
__device__ __forceinline__ void embed_body(const EArgs& A, int m0, int nh,
                                           float* Abuf0, float* Abuf1,
                                           unsigned short* Wbuf0, unsigned short* Wbuf1) {
    const int t = threadIdx.x, lane = t & 63, wid = t >> 6;
    const int l15 = lane & 15, l4 = lane >> 4;
    const int wr = wid >> 1, wc = wid & 1;
    const int S = A.S;
    const size_t S2 = (size_t)S * S;

    float* Ab[2] = { Abuf0, Abuf1 };
    unsigned short* Wbf[2] = { Wbuf0, Wbuf1 };

    // ---- per-lane A staging pointers: chunk i (cA = wid*4+i), lane covers
    // patch p = cA*8 + (lane>>3), phys slot = lane&7, logical kq = (lane&7)^(lane>>3)
    const int kqL = (lane & 7) ^ (lane >> 3);
    const float* aP[4];
#pragma unroll
    for (int i = 0; i < 4; ++i) {
        int p = (wid * 4 + i) * 8 + (lane >> 3);
        int m = m0 + p;
        int b = m >> A.lgNp, n = m & (A.Np - 1);
        int gy = n >> A.lgG, gx = n & ((1 << A.lgG) - 1);
        aP[i] = A.src + ((size_t)(b * 3) * S + gy * 16 + (kqL >> 2)) * (size_t)S
              + gx * 16 + (kqL & 3) * 4;
    }
    // ---- per-lane W staging pointers: chunk j (cW = wid*2+j)
    const unsigned short* wP[2];
#pragma unroll
    for (int j = 0; j < 2; ++j)
        wP[j] = A.Wb + (size_t)(nh * 8 + wid * 2 + j) * 12288 + lane * 8;

    auto stage = [&](int kt, int buf) {
        size_t aoff = (size_t)(kt >> 3) * S2 + (size_t)((kt & 7) * 2) * S;
#pragma unroll
        for (int i = 0; i < 4; ++i)
            GLOAD16(aP[i] + aoff, Ab[buf] + (wid * 4 + i) * 256);
#pragma unroll
        for (int j = 0; j < 2; ++j)
            GLOAD16(wP[j] + kt * 512, Wbf[buf] + (wid * 2 + j) * 512);
    };

    f32x4 acc[4][4];
#pragma unroll
    for (int i = 0; i < 4; ++i)
#pragma unroll
        for (int j = 0; j < 4; ++j) acc[i][j] = f32x4{0.f, 0.f, 0.f, 0.f};

    auto compute = [&](int c) {
        // A fragments: patch row p = wr*64+i*16+l15, logical kq {2l4, 2l4+1},
        // phys slot = kq ^ (p&7) = kq ^ (l15&7)
        bf16x8 pf[4];
#pragma unroll
        for (int i = 0; i < 4; ++i) {
            const char* base = (const char*)Ab[c] + (wr * 64 + i * 16 + l15) * 128;
            f32x4 lo = *(const f32x4*)(base + (((2 * l4) ^ (l15 & 7)) << 4));
            f32x4 hi = *(const f32x4*)(base + (((2 * l4 + 1) ^ (l15 & 7)) << 4));
            bf16x8 v;
#pragma unroll
            for (int e = 0; e < 4; ++e) { v[e] = (__bf16)lo[e]; v[4 + e] = (__bf16)hi[e]; }
            pf[i] = v;
        }
        // W fragments: d-tile wc*4+j, row d16 = l15, slot = l4 ^ ((l15>>1)&3)
        bf16x8 wf[4];
#pragma unroll
        for (int j = 0; j < 4; ++j) {
            const char* base = (const char*)Wbf[c] + (wc * 4 + j) * 1024;
            u16x8 r = *(const u16x8*)(base + l15 * 64 + ((l4 ^ ((l15 >> 1) & 3)) << 4));
            wf[j] = __builtin_bit_cast(bf16x8, r);
        }
#pragma unroll
        for (int i = 0; i < 4; ++i)
#pragma unroll
            for (int j = 0; j < 4; ++j) {
                if (TR) acc[i][j] = MFMA16(pf[i], wf[j], acc[i][j]);  // D[patch][d]
                else    acc[i][j] = MFMA16(wf[j], pf[i], acc[i][j]);  // D[d][patch]
            }
    };

    // ---- prologue: two tiles in flight
    stage(0, 0);
    stage(1, 1);

#pragma unroll 2
    for (int kt = 0; kt < 22; ++kt) {
        asm volatile("s_waitcnt vmcnt(6)" ::: "memory");   // tile kt landed
        __builtin_amdgcn_s_barrier();
        compute(kt & 1);
        asm volatile("s_waitcnt lgkmcnt(0)" ::: "memory"); // all LDS reads done
        __builtin_amdgcn_sched_barrier(0);
        __builtin_amdgcn_s_barrier();
        stage(kt + 2, kt & 1);                             // refill just-freed buf
    }
    // kt = 22
    asm volatile("s_waitcnt vmcnt(6)" ::: "memory");
    __builtin_amdgcn_s_barrier();
    compute(0);
    asm volatile("s_waitcnt lgkmcnt(0)" ::: "memory");
    __builtin_amdgcn_sched_barrier(0);
    __builtin_amdgcn_s_barrier();
    // kt = 23
    asm volatile("s_waitcnt vmcnt(0)" ::: "memory");
    __builtin_amdgcn_s_barrier();
    compute(1);

    // ---- epilogue (same as v3)
    if (!TR) {
#pragma unroll
        for (int j = 0; j < 4; ++j) {
            int d0 = nh * 128 + wc * 64 + j * 16 + l4 * 4;
            int hh = d0 >> 5, hd = d0 & 31;
            f32x4 bs = *(const f32x4*)&A.bias[d0];
#pragma unroll
            for (int i = 0; i < 4; ++i) {
                int p = m0 + wr * 64 + i * 16 + l15;
                int b = p >> A.lgNp, n = p & (A.Np - 1);
                f32x4 pv = *(const f32x4*)&A.pe[n * 256 + d0];
                bf16x4 o;
#pragma unroll
                for (int r = 0; r < 4; ++r)
                    o[r] = (__bf16)(acc[i][j][r] + bs[r] + pv[r]);
                *(bf16x4*)&A.dst[(((size_t)(b * 8 + hh)) * A.Np + n) * 32 + hd] = o;
            }
        }
    } else {
#pragma unroll
        for (int j = 0; j < 4; ++j) {
            int d = nh * 128 + wc * 64 + j * 16 + l15;
            int hh = d >> 5, hd = d & 31;
            float bsv = A.bias[d];
#pragma unroll
            for (int i = 0; i < 4; ++i) {
                int p0 = m0 + wr * 64 + i * 16 + l4 * 4;
                int b = p0 >> A.lgNp, n0 = p0 & (A.Np - 1);
                f32x4 pv = *(const f32x4*)&A.peT[(size_t)d * 1024 + n0];
                bf16x4 o;
#pragma unroll
                for (int r = 0; r < 4; ++r)
                    o[r] = (__bf16)(acc[i][j][r] + bsv + pv[r]);
                *(bf16x4*)&A.dst[(((size_t)(b * 8 + hh)) * 32 + hd) * (size_t)A.Np + n0] = o;
            }
        }
    }
}

__global__ __launch_bounds__(256, 2)
void embed4(EArgs A0, EArgs A1, EArgs A2, EArgs A3) {
    __shared__ float Abuf[2][4096];            // 2 x 16 KB (128 patches x 32 k, f32)
    __shared__ unsigned short Wbuf[2][4096];   // 2 x 8 KB (8 d-tiles x 1KB chunks)
    const int bx = blockIdx.x;
    EArgs A; int lbx;
    if      (bx < 256) { A = A0; lbx = bx; }
    else if (bx < 512) { A = A1; lbx = bx - 256; }
    else if (bx < 768) { A = A2; lbx = bx - 512; }
    else               { A = A3; lbx = bx - 768; }
    const int m0 = (lbx >> 1) * 128;
    const int nh = lbx & 1;
    if (A.trans) embed_body<true>(A, m0, nh, Abuf[0], Abuf[1], Wbuf[0], Wbuf[1]);
    else         embed_body<false>(A, m0, nh, Abuf[0], Abuf[1], Wbuf[0], Wbuf[1]);
}

// ---------------------------------------------------------------- stage 2: Ks softmax + KV
__global__ __launch_bounds__(512)
void s2kv_kernel(const unsigned short* __restrict__ ah_ws,
                 const unsigned short* __restrict__ kh_ws,
                 const unsigned short* __restrict__ vT_ws,
                 unsigned short* __restrict__ kvT_ws) {
    __shared__ unsigned short ahs[128][40];
    __shared__ unsigned short khs[128][40];
    __shared__ unsigned short vts[32][136];
    __shared__ unsigned short Ps[128][136];

    const int bid = blockIdx.x;
    const int half = bid & 1;
    const int h = (bid >> 1) & 7, b = bid >> 4;
    const int a0 = half * 128;
    const int t = threadIdx.x, lane = t & 63, wid = t >> 6;
    const int l15 = lane & 15, l4 = lane >> 4;
    const size_t bh = (size_t)(b * 8 + h);

    const unsigned short* ahp = ah_ws + (bh * 256 + a0) * 32;
    const unsigned short* khp = kh_ws + bh * 1024 * 32;
    const unsigned short* vtp = vT_ws + bh * 32 * 1024;

    {
        int row = t >> 2, kq = (t & 3) * 8;
        *(u16x8*)&ahs[row][kq] = *(const u16x8*)(ahp + row * 32 + kq);
    }
    __syncthreads();
    const bf16x8 af = *(const bf16x8*)&ahs[wid * 16 + l15][l4 * 8];

    const float scale = 0.17677669529663687f;
    float rs[4] = {0.f, 0.f, 0.f, 0.f};
    const f32x4 z = {0.f, 0.f, 0.f, 0.f};
    f32x4 kv[2];
    kv[0] = z; kv[1] = z;

    for (int kt = 0; kt < 8; ++kt) {
        const int n0 = kt * 128;
        __syncthreads();
        {
            int row = t >> 2, kq = (t & 3) * 8;
            *(u16x8*)&khs[row][kq] = *(const u16x8*)(khp + (size_t)(n0 + row) * 32 + kq);
        }
        {
            int row = t >> 4, cq = (t & 15) * 8;
            *(u16x8*)&vts[row][cq] = *(const u16x8*)(vtp + (size_t)row * 1024 + n0 + cq);
        }
        __syncthreads();
#pragma unroll
        for (int n16 = 0; n16 < 8; ++n16) {
            bf16x8 bfr = *(const bf16x8*)&khs[n16 * 16 + l15][l4 * 8];
            f32x4 s = MFMA16(af, bfr, z);
#pragma unroll
            for (int r = 0; r < 4; ++r) {
                float e = __expf(s[r] * scale);
                rs[r] += e;
                Ps[wid * 16 + l4 * 4 + r][n16 * 16 + l15] = f2bf(e);
            }
        }
        __syncthreads();
#pragma unroll
        for (int ks = 0; ks < 4; ++ks) {
            bf16x8 pa = *(const bf16x8*)&Ps[wid * 16 + l15][ks * 32 + l4 * 8];
#pragma unroll
            for (int n16 = 0; n16 < 2; ++n16) {
                bf16x8 vb = *(const bf16x8*)&vts[n16 * 16 + l15][ks * 32 + l4 * 8];
                kv[n16] = MFMA16(pa, vb, kv[n16]);
            }
        }
    }
#pragma unroll
    for (int r = 0; r < 4; ++r) {
        rs[r] += __shfl_xor(rs[r], 1, 64);
        rs[r] += __shfl_xor(rs[r], 2, 64);
        rs[r] += __shfl_xor(rs[r], 4, 64);
        rs[r] += __shfl_xor(rs[r], 8, 64);
    }
#pragma unroll
    for (int n16 = 0; n16 < 2; ++n16)
#pragma unroll
        for (int r = 0; r < 4; ++r) {
            int m = a0 + wid * 16 + l4 * 4 + r;
            int d = n16 * 16 + l15;
            kvT_ws[bh * 8192 + (size_t)d * 256 + m] = f2bf(kv[n16][r] / rs[r]);
        }
}

// ---------------------------------------------------------------- stage 3: Qs softmax + A + unshuffle
__global__ __launch_bounds__(256)
void qsa_kernel(const unsigned short* __restrict__ qh_ws,
                const unsigned short* __restrict__ ah_ws,
                const unsigned short* __restrict__ kvT_ws,
                float* __restrict__ out) {
    __shared__ unsigned short qhs[64][40];
    __shared__ unsigned short ahs[256][40];
    __shared__ unsigned short kvt[32][264];
    __shared__ unsigned short Ps[64][264];

    const int bid = blockIdx.x;
    const int qt = bid & 15, h = (bid >> 4) & 7, b = bid >> 7;
    const int m0 = qt * 64;
    const int t = threadIdx.x, lane = t & 63, wid = t >> 6;
    const int l15 = lane & 15, l4 = lane >> 4;
    const size_t bh = (size_t)(b * 8 + h);

    const unsigned short* qhp = qh_ws + (bh * 1024 + m0) * 32;
    const unsigned short* ahp = ah_ws + bh * 256 * 32;

    {
        int row = t >> 2, kq = (t & 3) * 8;
        *(u16x8*)&qhs[row][kq] = *(const u16x8*)(qhp + row * 32 + kq);
    }
    {
        *(u16x8*)&ahs[t][0]  = *(const u16x8*)(ahp + (size_t)t * 32);
        *(u16x8*)&ahs[t][8]  = *(const u16x8*)(ahp + (size_t)t * 32 + 8);
        *(u16x8*)&ahs[t][16] = *(const u16x8*)(ahp + (size_t)t * 32 + 16);
        *(u16x8*)&ahs[t][24] = *(const u16x8*)(ahp + (size_t)t * 32 + 24);
    }
#pragma unroll
    for (int i = 0; i < 4; ++i) {
        int chunk = t + i * 256;
        int row = chunk >> 5, cq = (chunk & 31) * 8;
        *(u16x8*)&kvt[row][cq] = *(const u16x8*)(kvT_ws + bh * 8192 + (size_t)row * 256 + cq);
    }
    __syncthreads();

    const bf16x8 qa = *(const bf16x8*)&qhs[wid * 16 + l15][l4 * 8];
    const float scale = 0.17677669529663687f;
    const f32x4 z = {0.f, 0.f, 0.f, 0.f};
    float rs[4] = {0.f, 0.f, 0.f, 0.f};
#pragma unroll
    for (int n16 = 0; n16 < 16; ++n16) {
        bf16x8 bfr = *(const bf16x8*)&ahs[n16 * 16 + l15][l4 * 8];
        f32x4 s = MFMA16(qa, bfr, z);
#pragma unroll
        for (int r = 0; r < 4; ++r) {
            float e = __expf(s[r] * scale);
            rs[r] += e;
            Ps[wid * 16 + l4 * 4 + r][n16 * 16 + l15] = f2bf(e);
        }
    }
#pragma unroll
    for (int r = 0; r < 4; ++r) {
        rs[r] += __shfl_xor(rs[r], 1, 64);
        rs[r] += __shfl_xor(rs[r], 2, 64);
        rs[r] += __shfl_xor(rs[r], 4, 64);
        rs[r] += __shfl_xor(rs[r], 8, 64);
    }
    __syncthreads();

    f32x4 o[2];
    o[0] = z; o[1] = z;
#pragma unroll
    for (int ks = 0; ks < 8; ++ks) {
        bf16x8 pa = *(const bf16x8*)&Ps[wid * 16 + l15][ks * 32 + l4 * 8];
#pragma unroll
        for (int n16 = 0; n16 < 2; ++n16) {
            bf16x8 kb = *(const bf16x8*)&kvt[n16 * 16 + l15][ks * 32 + l4 * 8];
            o[n16] = MFMA16(pa, kb, o[n16]);
        }
    }
#pragma unroll
    for (int n16 = 0; n16 < 2; ++n16) {
#pragma unroll
        for (int r = 0; r < 4; ++r) {
            int row = wid * 16 + l4 * 4 + r;
            int n = m0 + row;
            int gy = n >> 5, gx = n & 31;
            int hd = n16 * 16 + l15;
            int py = 2 * h + (hd >> 4), px = hd & 15;
            out[((size_t)b * 512 + gy * 16 + py) * 512 + gx * 16 + px] = o[n16][r] / rs[r];
        }
    }
}

// ---------------------------------------------------------------- launch
extern "C" void kernel_launch(void* const* d_in, const int* in_sizes, int n_in,
                              void* d_out, int out_size, void* d_ws, size_t ws_size,
                              hipStream_t stream) {
    (void)in_sizes; (void)n_in; (void)out_size; (void)ws_size;

    const float* q  = (const float*)d_in[0];
    const float* k  = (const float*)d_in[1];
    const float* v  = (const float*)d_in[2];
    const float* a  = (const float*)d_in[3];
    const float* wq = (const float*)d_in[4];
    const float* bq = (const float*)d_in[5];
    const float* wk = (const float*)d_in[6];
    const float* bk = (const float*)d_in[7];
    const float* wv = (const float*)d_in[8];
    const float* bv = (const float*)d_in[9];
    const float* wa = (const float*)d_in[10];
    const float* ba = (const float*)d_in[11];
    float* out = (float*)d_out;

    // ws layout. pe/peT dead after embed4; kvT aliases that region.
    char* ws = (char*)d_ws;
    float* pe           = (float*)(ws);                        // 1 MB @ 0
    float* peT          = (float*)(ws + 1048576);              // 1 MB @ 1M
    unsigned short* Wb  = (unsigned short*)(ws + 2097152);     // 1.5 MB @ 2M
    unsigned short* kvT = (unsigned short*)(ws);               // 2 MB (aliases pe+peT)
    unsigned short* qh  = (unsigned short*)(ws + 3670016);     // 8 MB
    unsigned short* kh  = (unsigned short*)(ws + 12058624);    // 8 MB
    unsigned short* ah  = (unsigned short*)(ws + 20447232);    // 2 MB
    unsigned short* vT  = (unsigned short*)(ws + 22544384);    // 8 MB
    // total 30,932,992 bytes

    prep<<<2048, 256, 0, stream>>>(pe, peT, Wb, wq, wk, wv, wa);

    EArgs Aq = { q, Wb,              bq, pe, peT, qh, 1024, 10, 5, 512, 0 };
    EArgs Ak = { k, Wb + 196608,     bk, pe, peT, kh, 1024, 10, 5, 512, 0 };
    EArgs Av = { v, Wb + 2 * 196608, bv, pe, peT, vT, 1024, 10, 5, 512, 1 };
    EArgs Aa = { a, Wb + 3 * 196608, ba, pe, peT, ah,  256,  8, 4, 256, 0 };
    embed4<<<832, 256, 0, stream>>>(Aq, Ak, Av, Aa);

    s2kv_kernel<<<256, 512, 0, stream>>>(ah, kh, vT, kvT);
    qsa_kernel<<<2048, 256, 0, stream>>>(qh, ah, kvT, out);
}

// Round 5
// 106.315 us; speedup vs baseline: 1.1056x; 1.1056x over previous
//
#include <hip/hip_runtime.h>
#include <cstdint>
#include <cstddef>

typedef __bf16 bf16x8 __attribute__((ext_vector_type(8)));
typedef __bf16 bf16x4 __attribute__((ext_vector_type(4)));
typedef float f32x4 __attribute__((ext_vector_type(4)));
typedef unsigned short u16x4 __attribute__((ext_vector_type(4)));
typedef unsigned short u16x8 __attribute__((ext_vector_type(8)));

#define MFMA16(a, b, c) __builtin_amdgcn_mfma_f32_16x16x32_bf16(a, b, c, 0, 0, 0)

// async global->LDS, 16B per lane, LDS dest = wave-uniform base + lane*16
#define GLOAD16(g, l)                                                          \
    __builtin_amdgcn_global_load_lds(                                          \
        (const __attribute__((address_space(1))) unsigned int*)(g),            \
        (__attribute__((address_space(3))) unsigned int*)(l), 16, 0, 0)

__device__ __forceinline__ unsigned short f2bf(float f) {
    unsigned u = __builtin_bit_cast(unsigned, f);
    u = (u + 0x7FFFu + ((u >> 16) & 1u)) >> 16;   // RNE
    return (unsigned short)u;
}

// ---------------------------------------------------------------- prep:
// blocks [0,1024)    : pe[n][d]  (f32, n-major)
// blocks [1024,1280) : peT[d][n] (f32, d-major) for the V-transposed epilogue
// blocks [1280,2048) : weights f32 -> bf16, chunked per (d-tile, k-tile):
//   1KB chunk = [d&15][slot][e]; slot = (kq>>1) ^ ((d16>>1)&3)  (bank swizzle)
__global__ __launch_bounds__(256)
void prep(float* __restrict__ pe, float* __restrict__ peT, unsigned short* __restrict__ Wb,
          const float* __restrict__ w0, const float* __restrict__ w1,
          const float* __restrict__ w2, const float* __restrict__ w3) {
    const int bx = blockIdx.x, t = threadIdx.x;
    const float LC = 0.03597789207808881f;  // ln(10000)/256
    if (bx < 1024) {
        int n = bx, d = t;
        float div = expf(-(float)(2 * (d >> 1)) * LC);
        float ang = (float)n * div;
        pe[n * 256 + d] = (d & 1) ? cosf(ang) : sinf(ang);
    } else if (bx < 1280) {
        int d = bx - 1024;
        float div = expf(-(float)(2 * (d >> 1)) * LC);
        f32x4 o;
        int n0 = t * 4;
#pragma unroll
        for (int e = 0; e < 4; ++e) {
            float ang = (float)(n0 + e) * div;
            o[e] = (d & 1) ? cosf(ang) : sinf(ang);
        }
        *(f32x4*)&peT[(size_t)d * 1024 + n0] = o;
    } else {
        int i = bx - 1280;                 // 0..767, 192 blocks per tensor
        int tensor = i / 192, blk = i - tensor * 192;
        const float* w = (tensor == 0) ? w0 : (tensor == 1) ? w1 : (tensor == 2) ? w2 : w3;
        int idx4 = blk * 256 + t;          // f32x4 index
        int d = idx4 / 192;                // 192 quads per 768-row
        int kq4 = idx4 - d * 192;          // k-quad 0..191
        f32x4 v = *(const f32x4*)(w + (size_t)idx4 * 4);
        u16x4 o;
#pragma unroll
        for (int e = 0; e < 4; ++e) o[e] = f2bf(v[e]);
        int d16 = d & 15, kq_in = kq4 & 7;
        int slot = (kq_in >> 1) ^ ((d16 >> 1) & 3);
        unsigned short* dst = Wb + (size_t)tensor * 196608
                            + (d >> 4) * 12288 + (kq4 >> 3) * 512
                            + d16 * 32 + slot * 8 + (kq_in & 1) * 4;
        *(u16x4*)dst = o;
    }
}

// ---------------------------------------------------------------- patch embed v5
// 64 patches x 128 d per block (32 KB LDS -> 5 blocks/CU), 4 waves (2x2),
// wave-tile 32 patches x 64 d. BK=32, 24 K-steps. All staging via
// global_load_lds; counted vmcnt(4) across raw s_barriers; A f32 in LDS,
// cvt at frag read. Latency hidden by cross-block TLP (~20 waves/CU).
struct EArgs {
    const float* src;
    const unsigned short* Wb;   // chunked/swizzled bf16 weights (196608 elems)
    const float* bias;
    const float* pe;            // (1024,256) n-major
    const float* peT;           // (256,1024) d-major
    unsigned short* dst;
    int Np, lgNp, lgG, S, trans;
};

template<bool TR>
__device__ __forceinline__ void embed_body(const EArgs& A, int m0, int nh,
                                           float* Abuf0, float* Abuf1,
                                           unsigned short* Wbuf0, unsigned short* Wbuf1) {
    const int t = threadIdx.x, lane = t & 63, wid = t >> 6;
    const int l15 = lane & 15, l4 = lane >> 4;
    const int wr = wid >> 1, wc = wid & 1;
    const int S = A.S;
    const size_t S2 = (size_t)S * S;

    float* Ab[2] = { Abuf0, Abuf1 };
    unsigned short* Wbf[2] = { Wbuf0, Wbuf1 };

    // ---- per-lane A staging pointers: chunk cA = wid*2+i covers patches
    // cA*8..cA*8+7; lane>>3 = patch-in-chunk, phys slot = lane&7,
    // logical kq = (lane&7)^(lane>>3)  (both-sides XOR swizzle)
    const int kqL = (lane & 7) ^ (lane >> 3);
    const float* aP[2];
#pragma unroll
    for (int i = 0; i < 2; ++i) {
        int p = (wid * 2 + i) * 8 + (lane >> 3);
        int m = m0 + p;
        int b = m >> A.lgNp, n = m & (A.Np - 1);
        int gy = n >> A.lgG, gx = n & ((1 << A.lgG) - 1);
        aP[i] = A.src + ((size_t)(b * 3) * S + gy * 16 + (kqL >> 2)) * (size_t)S
              + gx * 16 + (kqL & 3) * 4;
    }
    // ---- per-lane W staging pointers: chunk cW = wid*2+j (8 d-tiles total)
    const unsigned short* wP[2];
#pragma unroll
    for (int j = 0; j < 2; ++j)
        wP[j] = A.Wb + (size_t)(nh * 8 + wid * 2 + j) * 12288 + lane * 8;

    auto stage = [&](int kt, int buf) {
        size_t aoff = (size_t)(kt >> 3) * S2 + (size_t)((kt & 7) * 2) * S;
#pragma unroll
        for (int i = 0; i < 2; ++i)
            GLOAD16(aP[i] + aoff, Ab[buf] + (wid * 2 + i) * 256);
#pragma unroll
        for (int j = 0; j < 2; ++j)
            GLOAD16(wP[j] + kt * 512, Wbf[buf] + (wid * 2 + j) * 512);
    };

    f32x4 acc[2][4];
#pragma unroll
    for (int i = 0; i < 2; ++i)
#pragma unroll
        for (int j = 0; j < 4; ++j) acc[i][j] = f32x4{0.f, 0.f, 0.f, 0.f};

    auto compute = [&](int c) {
        // A frags: patch row p = wr*32 + i*16 + l15, logical kq {2l4, 2l4+1},
        // phys slot = kq ^ (p&7) = kq ^ (l15&7)
        bf16x8 pf[2];
#pragma unroll
        for (int i = 0; i < 2; ++i) {
            const char* base = (const char*)Ab[c] + (wr * 32 + i * 16 + l15) * 128;
            f32x4 lo = *(const f32x4*)(base + (((2 * l4) ^ (l15 & 7)) << 4));
            f32x4 hi = *(const f32x4*)(base + (((2 * l4 + 1) ^ (l15 & 7)) << 4));
            bf16x8 v;
#pragma unroll
            for (int e = 0; e < 4; ++e) { v[e] = (__bf16)lo[e]; v[4 + e] = (__bf16)hi[e]; }
            pf[i] = v;
        }
        // W frags: d-tile wc*4+j, row d16 = l15, slot = l4 ^ ((l15>>1)&3)
        bf16x8 wf[4];
#pragma unroll
        for (int j = 0; j < 4; ++j) {
            const char* base = (const char*)Wbf[c] + (wc * 4 + j) * 1024;
            u16x8 r = *(const u16x8*)(base + l15 * 64 + ((l4 ^ ((l15 >> 1) & 3)) << 4));
            wf[j] = __builtin_bit_cast(bf16x8, r);
        }
#pragma unroll
        for (int i = 0; i < 2; ++i)
#pragma unroll
            for (int j = 0; j < 4; ++j) {
                if (TR) acc[i][j] = MFMA16(pf[i], wf[j], acc[i][j]);  // D[patch][d]
                else    acc[i][j] = MFMA16(wf[j], pf[i], acc[i][j]);  // D[d][patch]
            }
    };

    // ---- prologue: two tiles in flight
    stage(0, 0);
    stage(1, 1);

#pragma unroll 2
    for (int kt = 0; kt < 22; ++kt) {
        asm volatile("s_waitcnt vmcnt(4)" ::: "memory");   // tile kt landed
        __builtin_amdgcn_s_barrier();
        compute(kt & 1);
        asm volatile("s_waitcnt lgkmcnt(0)" ::: "memory"); // all LDS reads done
        __builtin_amdgcn_sched_barrier(0);
        __builtin_amdgcn_s_barrier();
        stage(kt + 2, kt & 1);                             // refill just-freed buf
    }
    // kt = 22
    asm volatile("s_waitcnt vmcnt(4)" ::: "memory");
    __builtin_amdgcn_s_barrier();
    compute(0);
    asm volatile("s_waitcnt lgkmcnt(0)" ::: "memory");
    __builtin_amdgcn_sched_barrier(0);
    __builtin_amdgcn_s_barrier();
    // kt = 23
    asm volatile("s_waitcnt vmcnt(0)" ::: "memory");
    __builtin_amdgcn_s_barrier();
    compute(1);

    // ---- epilogue
    if (!TR) {
#pragma unroll
        for (int j = 0; j < 4; ++j) {
            int d0 = nh * 128 + wc * 64 + j * 16 + l4 * 4;
            int hh = d0 >> 5, hd = d0 & 31;
            f32x4 bs = *(const f32x4*)&A.bias[d0];
#pragma unroll
            for (int i = 0; i < 2; ++i) {
                int p = m0 + wr * 32 + i * 16 + l15;
                int b = p >> A.lgNp, n = p & (A.Np - 1);
                f32x4 pv = *(const f32x4*)&A.pe[n * 256 + d0];
                bf16x4 o;
#pragma unroll
                for (int r = 0; r < 4; ++r)
                    o[r] = (__bf16)(acc[i][j][r] + bs[r] + pv[r]);
                *(bf16x4*)&A.dst[(((size_t)(b * 8 + hh)) * A.Np + n) * 32 + hd] = o;
            }
        }
    } else {
#pragma unroll
        for (int j = 0; j < 4; ++j) {
            int d = nh * 128 + wc * 64 + j * 16 + l15;
            int hh = d >> 5, hd = d & 31;
            float bsv = A.bias[d];
#pragma unroll
            for (int i = 0; i < 2; ++i) {
                int p0 = m0 + wr * 32 + i * 16 + l4 * 4;
                int b = p0 >> A.lgNp, n0 = p0 & (A.Np - 1);
                f32x4 pv = *(const f32x4*)&A.peT[(size_t)d * 1024 + n0];
                bf16x4 o;
#pragma unroll
                for (int r = 0; r < 4; ++r)
                    o[r] = (__bf16)(acc[i][j][r] + bsv + pv[r]);
                *(bf16x4*)&A.dst[(((size_t)(b * 8 + hh)) * 32 + hd) * (size_t)A.Np + n0] = o;
            }
        }
    }
}

__global__ __launch_bounds__(256, 4)
void embed5(EArgs A0, EArgs A1, EArgs A2, EArgs A3) {
    __shared__ float Abuf[2][2048];            // 2 x 8 KB (64 patches x 32 k, f32)
    __shared__ unsigned short Wbuf[2][4096];   // 2 x 8 KB (8 d-tiles x 1KB chunks)
    const int bx = blockIdx.x;
    EArgs A; int lbx;
    if      (bx < 512)  { A = A0; lbx = bx; }
    else if (bx < 1024) { A = A1; lbx = bx - 512; }
    else if (bx < 1536) { A = A2; lbx = bx - 1024; }
    else                { A = A3; lbx = bx - 1536; }
    const int m0 = (lbx >> 1) * 64;
    const int nh = lbx & 1;
    if (A.trans) embed_body<true>(A, m0, nh, Abuf[0], Abuf[1], Wbuf[0], Wbuf[1]);
    else         embed_body<false>(A, m0, nh, Abuf[0], Abuf[1], Wbuf[0], Wbuf[1]);
}

// ---------------------------------------------------------------- stage 2: Ks softmax + KV
__global__ __launch_bounds__(512)
void s2kv_kernel(const unsigned short* __restrict__ ah_ws,
                 const unsigned short* __restrict__ kh_ws,
                 const unsigned short* __restrict__ vT_ws,
                 unsigned short* __restrict__ kvT_ws) {
    __shared__ unsigned short ahs[128][40];
    __shared__ unsigned short khs[128][40];
    __shared__ unsigned short vts[32][136];
    __shared__ unsigned short Ps[128][136];

    const int bid = blockIdx.x;
    const int half = bid & 1;
    const int h = (bid >> 1) & 7, b = bid >> 4;
    const int a0 = half * 128;
    const int t = threadIdx.x, lane = t & 63, wid = t >> 6;
    const int l15 = lane & 15, l4 = lane >> 4;
    const size_t bh = (size_t)(b * 8 + h);

    const unsigned short* ahp = ah_ws + (bh * 256 + a0) * 32;
    const unsigned short* khp = kh_ws + bh * 1024 * 32;
    const unsigned short* vtp = vT_ws + bh * 32 * 1024;

    {
        int row = t >> 2, kq = (t & 3) * 8;
        *(u16x8*)&ahs[row][kq] = *(const u16x8*)(ahp + row * 32 + kq);
    }
    __syncthreads();
    const bf16x8 af = *(const bf16x8*)&ahs[wid * 16 + l15][l4 * 8];

    const float scale = 0.17677669529663687f;
    float rs[4] = {0.f, 0.f, 0.f, 0.f};
    const f32x4 z = {0.f, 0.f, 0.f, 0.f};
    f32x4 kv[2];
    kv[0] = z; kv[1] = z;

    for (int kt = 0; kt < 8; ++kt) {
        const int n0 = kt * 128;
        __syncthreads();
        {
            int row = t >> 2, kq = (t & 3) * 8;
            *(u16x8*)&khs[row][kq] = *(const u16x8*)(khp + (size_t)(n0 + row) * 32 + kq);
        }
        {
            int row = t >> 4, cq = (t & 15) * 8;
            *(u16x8*)&vts[row][cq] = *(const u16x8*)(vtp + (size_t)row * 1024 + n0 + cq);
        }
        __syncthreads();
#pragma unroll
        for (int n16 = 0; n16 < 8; ++n16) {
            bf16x8 bfr = *(const bf16x8*)&khs[n16 * 16 + l15][l4 * 8];
            f32x4 s = MFMA16(af, bfr, z);
#pragma unroll
            for (int r = 0; r < 4; ++r) {
                float e = __expf(s[r] * scale);
                rs[r] += e;
                Ps[wid * 16 + l4 * 4 + r][n16 * 16 + l15] = f2bf(e);
            }
        }
        __syncthreads();
#pragma unroll
        for (int ks = 0; ks < 4; ++ks) {
            bf16x8 pa = *(const bf16x8*)&Ps[wid * 16 + l15][ks * 32 + l4 * 8];
#pragma unroll
            for (int n16 = 0; n16 < 2; ++n16) {
                bf16x8 vb = *(const bf16x8*)&vts[n16 * 16 + l15][ks * 32 + l4 * 8];
                kv[n16] = MFMA16(pa, vb, kv[n16]);
            }
        }
    }
#pragma unroll
    for (int r = 0; r < 4; ++r) {
        rs[r] += __shfl_xor(rs[r], 1, 64);
        rs[r] += __shfl_xor(rs[r], 2, 64);
        rs[r] += __shfl_xor(rs[r], 4, 64);
        rs[r] += __shfl_xor(rs[r], 8, 64);
    }
#pragma unroll
    for (int n16 = 0; n16 < 2; ++n16)
#pragma unroll
        for (int r = 0; r < 4; ++r) {
            int m = a0 + wid * 16 + l4 * 4 + r;
            int d = n16 * 16 + l15;
            kvT_ws[bh * 8192 + (size_t)d * 256 + m] = f2bf(kv[n16][r] / rs[r]);
        }
}

// ---------------------------------------------------------------- stage 3: Qs softmax + A + unshuffle
__global__ __launch_bounds__(256)
void qsa_kernel(const unsigned short* __restrict__ qh_ws,
                const unsigned short* __restrict__ ah_ws,
                const unsigned short* __restrict__ kvT_ws,
                float* __restrict__ out) {
    __shared__ unsigned short qhs[64][40];
    __shared__ unsigned short ahs[256][40];
    __shared__ unsigned short kvt[32][264];
    __shared__ unsigned short Ps[64][264];

    const int bid = blockIdx.x;
    const int qt = bid & 15, h = (bid >> 4) & 7, b = bid >> 7;
    const int m0 = qt * 64;
    const int t = threadIdx.x, lane = t & 63, wid = t >> 6;
    const int l15 = lane & 15, l4 = lane >> 4;
    const size_t bh = (size_t)(b * 8 + h);

    const unsigned short* qhp = qh_ws + (bh * 1024 + m0) * 32;
    const unsigned short* ahp = ah_ws + bh * 256 * 32;

    {
        int row = t >> 2, kq = (t & 3) * 8;
        *(u16x8*)&qhs[row][kq] = *(const u16x8*)(qhp + row * 32 + kq);
    }
    {
        *(u16x8*)&ahs[t][0]  = *(const u16x8*)(ahp + (size_t)t * 32);
        *(u16x8*)&ahs[t][8]  = *(const u16x8*)(ahp + (size_t)t * 32 + 8);
        *(u16x8*)&ahs[t][16] = *(const u16x8*)(ahp + (size_t)t * 32 + 16);
        *(u16x8*)&ahs[t][24] = *(const u16x8*)(ahp + (size_t)t * 32 + 24);
    }
#pragma unroll
    for (int i = 0; i < 4; ++i) {
        int chunk = t + i * 256;
        int row = chunk >> 5, cq = (chunk & 31) * 8;
        *(u16x8*)&kvt[row][cq] = *(const u16x8*)(kvT_ws + bh * 8192 + (size_t)row * 256 + cq);
    }
    __syncthreads();

    const bf16x8 qa = *(const bf16x8*)&qhs[wid * 16 + l15][l4 * 8];
    const float scale = 0.17677669529663687f;
    const f32x4 z = {0.f, 0.f, 0.f, 0.f};
    float rs[4] = {0.f, 0.f, 0.f, 0.f};
#pragma unroll
    for (int n16 = 0; n16 < 16; ++n16) {
        bf16x8 bfr = *(const bf16x8*)&ahs[n16 * 16 + l15][l4 * 8];
        f32x4 s = MFMA16(qa, bfr, z);
#pragma unroll
        for (int r = 0; r < 4; ++r) {
            float e = __expf(s[r] * scale);
            rs[r] += e;
            Ps[wid * 16 + l4 * 4 + r][n16 * 16 + l15] = f2bf(e);
        }
    }
#pragma unroll
    for (int r = 0; r < 4; ++r) {
        rs[r] += __shfl_xor(rs[r], 1, 64);
        rs[r] += __shfl_xor(rs[r], 2, 64);
        rs[r] += __shfl_xor(rs[r], 4, 64);
        rs[r] += __shfl_xor(rs[r], 8, 64);
    }
    __syncthreads();

    f32x4 o[2];
    o[0] = z; o[1] = z;
#pragma unroll
    for (int ks = 0; ks < 8; ++ks) {
        bf16x8 pa = *(const bf16x8*)&Ps[wid * 16 + l15][ks * 32 + l4 * 8];
#pragma unroll
        for (int n16 = 0; n16 < 2; ++n16) {
            bf16x8 kb = *(const bf16x8*)&kvt[n16 * 16 + l15][ks * 32 + l4 * 8];
            o[n16] = MFMA16(pa, kb, o[n16]);
        }
    }
#pragma unroll
    for (int n16 = 0; n16 < 2; ++n16) {
#pragma unroll
        for (int r = 0; r < 4; ++r) {
            int row = wid * 16 + l4 * 4 + r;
            int n = m0 + row;
            int gy = n >> 5, gx = n & 31;
            int hd = n16 * 16 + l15;
            int py = 2 * h + (hd >> 4), px = hd & 15;
            out[((size_t)b * 512 + gy * 16 + py) * 512 + gx * 16 + px] = o[n16][r] / rs[r];
        }
    }
}

// ---------------------------------------------------------------- launch
extern "C" void kernel_launch(void* const* d_in, const int* in_sizes, int n_in,
                              void* d_out, int out_size, void* d_ws, size_t ws_size,
                              hipStream_t stream) {
    (void)in_sizes; (void)n_in; (void)out_size; (void)ws_size;

    const float* q  = (const float*)d_in[0];
    const float* k  = (const float*)d_in[1];
    const float* v  = (const float*)d_in[2];
    const float* a  = (const float*)d_in[3];
    const float* wq = (const float*)d_in[4];
    const float* bq = (const float*)d_in[5];
    const float* wk = (const float*)d_in[6];
    const float* bk = (const float*)d_in[7];
    const float* wv = (const float*)d_in[8];
    const float* bv = (const float*)d_in[9];
    const float* wa = (const float*)d_in[10];
    const float* ba = (const float*)d_in[11];
    float* out = (float*)d_out;

    // ws layout. pe/peT dead after embed5; kvT aliases that region.
    char* ws = (char*)d_ws;
    float* pe           = (float*)(ws);                        // 1 MB @ 0
    float* peT          = (float*)(ws + 1048576);              // 1 MB @ 1M
    unsigned short* Wb  = (unsigned short*)(ws + 2097152);     // 1.5 MB @ 2M
    unsigned short* kvT = (unsigned short*)(ws);               // 2 MB (aliases pe+peT)
    unsigned short* qh  = (unsigned short*)(ws + 3670016);     // 8 MB
    unsigned short* kh  = (unsigned short*)(ws + 12058624);    // 8 MB
    unsigned short* ah  = (unsigned short*)(ws + 20447232);    // 2 MB
    unsigned short* vT  = (unsigned short*)(ws + 22544384);    // 8 MB
    // total 30,932,992 bytes

    prep<<<2048, 256, 0, stream>>>(pe, peT, Wb, wq, wk, wv, wa);

    EArgs Aq = { q, Wb,              bq, pe, peT, qh, 1024, 10, 5, 512, 0 };
    EArgs Ak = { k, Wb + 196608,     bk, pe, peT, kh, 1024, 10, 5, 512, 0 };
    EArgs Av = { v, Wb + 2 * 196608, bv, pe, peT, vT, 1024, 10, 5, 512, 1 };
    EArgs Aa = { a, Wb + 3 * 196608, ba, pe, peT, ah,  256,  8, 4, 256, 0 };
    embed5<<<1664, 256, 0, stream>>>(Aq, Ak, Av, Aa);

    s2kv_kernel<<<256, 512, 0, stream>>>(ah, kh, vT, kvT);
    qsa_kernel<<<2048, 256, 0, stream>>>(qh, ah, kvT, out);
}